// Round 7
// baseline (237.978 us; speedup 1.0000x reference)
//
#include <hip/hip_runtime.h>

#define BB 128
#define FF 512

typedef float v4f __attribute__((ext_vector_type(4)));

// Round-7: MLP scaling point n=4. r6 confirmed per-wave outstanding-read
// bytes as the binding resource (2 rows/wave: +9%). 4 rows/wave at stride
// 16384 (=32*512: j constant, w/ps amortized 4x, b advances by 32). All 8
// NT hebb loads issue first; 4 independent FMA chains + 4 interleaved
// butterflies give 4x ILP over the reduce/tanh chain. ~105 VGPR keeps
// 4-5 waves/SIMD -> 128-160 KB/CU hebb reads in flight (vs 112 at r6).
// n=8 rejected: ~180 VGPR -> 2 waves/SIMD cancels the MLP gain.
__global__ __launch_bounds__(256) void PlasticLinearRec_kernel(
    const float* __restrict__ input,
    const float* __restrict__ last_out,
    const float* __restrict__ hebb,
    const float* __restrict__ weight,
    const float* __restrict__ ps,
    const float* __restrict__ lr_p,
    float* __restrict__ out,       // B*F
    float* __restrict__ hebb_new)  // B*F*F
{
    const int wave = threadIdx.x >> 6;
    const int lane = threadIdx.x & 63;
    const int wid  = blockIdx.x * 4 + wave;     // 0 .. 16383
    const int j    = wid & (FF - 1);
    const int b0   = wid >> 9;                  // 0..31

    const int k0 = lane * 4;
    const int k1 = 256 + lane * 4;

    const size_t R  = (size_t)16384 * FF;       // row-group stride (floats)
    const size_t ha = (size_t)wid * FF;
    const size_t hb = ha + R;
    const size_t hc = ha + 2 * R;
    const size_t hd = ha + 3 * R;
    const int    wb = j * FF;
    const int    la = b0 * FF;                  // b = b0
    const int    lb = la + 32 * FF;             // b = b0+32
    const int    lc = la + 64 * FF;             // b = b0+64
    const int    ld = la + 96 * FF;             // b = b0+96

    // ---- 8 NT streaming loads first: 8 KB/wave in flight ----
    const v4f h0a = __builtin_nontemporal_load((const v4f*)(hebb + ha + k0));
    const v4f h1a = __builtin_nontemporal_load((const v4f*)(hebb + ha + k1));
    const v4f h0b = __builtin_nontemporal_load((const v4f*)(hebb + hb + k0));
    const v4f h1b = __builtin_nontemporal_load((const v4f*)(hebb + hb + k1));
    const v4f h0c = __builtin_nontemporal_load((const v4f*)(hebb + hc + k0));
    const v4f h1c = __builtin_nontemporal_load((const v4f*)(hebb + hc + k1));
    const v4f h0d = __builtin_nontemporal_load((const v4f*)(hebb + hd + k0));
    const v4f h1d = __builtin_nontemporal_load((const v4f*)(hebb + hd + k1));

    // ---- cached (L2/L3-hot) operands ----
    const v4f w0  = *(const v4f*)(weight   + wb + k0);
    const v4f w1  = *(const v4f*)(weight   + wb + k1);
    const v4f p0  = *(const v4f*)(ps       + wb + k0);
    const v4f p1  = *(const v4f*)(ps       + wb + k1);
    const v4f l0a = *(const v4f*)(last_out + la + k0);
    const v4f l1a = *(const v4f*)(last_out + la + k1);
    const v4f l0b = *(const v4f*)(last_out + lb + k0);
    const v4f l1b = *(const v4f*)(last_out + lb + k1);
    const v4f l0c = *(const v4f*)(last_out + lc + k0);
    const v4f l1c = *(const v4f*)(last_out + lc + k1);
    const v4f l0d = *(const v4f*)(last_out + ld + k0);
    const v4f l1d = *(const v4f*)(last_out + ld + k1);
    const float ia = input[la + j];
    const float ib = input[lb + j];
    const float ic = input[lc + j];
    const float id = input[ld + j];
    const float lr = lr_p[0];

    // ---- 4 independent FMA chains, interleaved ----
    float aa, ab, ac, ad;
    aa = l0a.x * fmaf(p0.x, h0a.x, w0.x);
    ab = l0b.x * fmaf(p0.x, h0b.x, w0.x);
    ac = l0c.x * fmaf(p0.x, h0c.x, w0.x);
    ad = l0d.x * fmaf(p0.x, h0d.x, w0.x);
    aa = fmaf(l0a.y, fmaf(p0.y, h0a.y, w0.y), aa);
    ab = fmaf(l0b.y, fmaf(p0.y, h0b.y, w0.y), ab);
    ac = fmaf(l0c.y, fmaf(p0.y, h0c.y, w0.y), ac);
    ad = fmaf(l0d.y, fmaf(p0.y, h0d.y, w0.y), ad);
    aa = fmaf(l0a.z, fmaf(p0.z, h0a.z, w0.z), aa);
    ab = fmaf(l0b.z, fmaf(p0.z, h0b.z, w0.z), ab);
    ac = fmaf(l0c.z, fmaf(p0.z, h0c.z, w0.z), ac);
    ad = fmaf(l0d.z, fmaf(p0.z, h0d.z, w0.z), ad);
    aa = fmaf(l0a.w, fmaf(p0.w, h0a.w, w0.w), aa);
    ab = fmaf(l0b.w, fmaf(p0.w, h0b.w, w0.w), ab);
    ac = fmaf(l0c.w, fmaf(p0.w, h0c.w, w0.w), ac);
    ad = fmaf(l0d.w, fmaf(p0.w, h0d.w, w0.w), ad);
    aa = fmaf(l1a.x, fmaf(p1.x, h1a.x, w1.x), aa);
    ab = fmaf(l1b.x, fmaf(p1.x, h1b.x, w1.x), ab);
    ac = fmaf(l1c.x, fmaf(p1.x, h1c.x, w1.x), ac);
    ad = fmaf(l1d.x, fmaf(p1.x, h1d.x, w1.x), ad);
    aa = fmaf(l1a.y, fmaf(p1.y, h1a.y, w1.y), aa);
    ab = fmaf(l1b.y, fmaf(p1.y, h1b.y, w1.y), ab);
    ac = fmaf(l1c.y, fmaf(p1.y, h1c.y, w1.y), ac);
    ad = fmaf(l1d.y, fmaf(p1.y, h1d.y, w1.y), ad);
    aa = fmaf(l1a.z, fmaf(p1.z, h1a.z, w1.z), aa);
    ab = fmaf(l1b.z, fmaf(p1.z, h1b.z, w1.z), ab);
    ac = fmaf(l1c.z, fmaf(p1.z, h1c.z, w1.z), ac);
    ad = fmaf(l1d.z, fmaf(p1.z, h1d.z, w1.z), ad);
    aa = fmaf(l1a.w, fmaf(p1.w, h1a.w, w1.w), aa);
    ab = fmaf(l1b.w, fmaf(p1.w, h1b.w, w1.w), ab);
    ac = fmaf(l1c.w, fmaf(p1.w, h1c.w, w1.w), ac);
    ad = fmaf(l1d.w, fmaf(p1.w, h1d.w, w1.w), ad);

    // ---- 4 interleaved 64-lane butterflies ----
    #pragma unroll
    for (int off = 32; off > 0; off >>= 1) {
        aa += __shfl_xor(aa, off, 64);
        ab += __shfl_xor(ab, off, 64);
        ac += __shfl_xor(ac, off, 64);
        ad += __shfl_xor(ad, off, 64);
    }

    const float oa = tanhf(aa + ia);
    const float ob = tanhf(ab + ib);
    const float oc = tanhf(ac + ic);
    const float od = tanhf(ad + id);
    const float ca = lr * oa;
    const float cb = lr * ob;
    const float cc = lr * oc;
    const float cd = lr * od;

    if (lane == 0) {
        out[la + j] = oa;
        out[lb + j] = ob;
        out[lc + j] = oc;
        out[ld + j] = od;
    }

    v4f n0, n1;
    n0.x = fmaf(ca, l0a.x - oa * h0a.x, h0a.x);
    n0.y = fmaf(ca, l0a.y - oa * h0a.y, h0a.y);
    n0.z = fmaf(ca, l0a.z - oa * h0a.z, h0a.z);
    n0.w = fmaf(ca, l0a.w - oa * h0a.w, h0a.w);
    n1.x = fmaf(ca, l1a.x - oa * h1a.x, h1a.x);
    n1.y = fmaf(ca, l1a.y - oa * h1a.y, h1a.y);
    n1.z = fmaf(ca, l1a.z - oa * h1a.z, h1a.z);
    n1.w = fmaf(ca, l1a.w - oa * h1a.w, h1a.w);
    __builtin_nontemporal_store(n0, (v4f*)(hebb_new + ha + k0));
    __builtin_nontemporal_store(n1, (v4f*)(hebb_new + ha + k1));

    n0.x = fmaf(cb, l0b.x - ob * h0b.x, h0b.x);
    n0.y = fmaf(cb, l0b.y - ob * h0b.y, h0b.y);
    n0.z = fmaf(cb, l0b.z - ob * h0b.z, h0b.z);
    n0.w = fmaf(cb, l0b.w - ob * h0b.w, h0b.w);
    n1.x = fmaf(cb, l1b.x - ob * h1b.x, h1b.x);
    n1.y = fmaf(cb, l1b.y - ob * h1b.y, h1b.y);
    n1.z = fmaf(cb, l1b.z - ob * h1b.z, h1b.z);
    n1.w = fmaf(cb, l1b.w - ob * h1b.w, h1b.w);
    __builtin_nontemporal_store(n0, (v4f*)(hebb_new + hb + k0));
    __builtin_nontemporal_store(n1, (v4f*)(hebb_new + hb + k1));

    n0.x = fmaf(cc, l0c.x - oc * h0c.x, h0c.x);
    n0.y = fmaf(cc, l0c.y - oc * h0c.y, h0c.y);
    n0.z = fmaf(cc, l0c.z - oc * h0c.z, h0c.z);
    n0.w = fmaf(cc, l0c.w - oc * h0c.w, h0c.w);
    n1.x = fmaf(cc, l1c.x - oc * h1c.x, h1c.x);
    n1.y = fmaf(cc, l1c.y - oc * h1c.y, h1c.y);
    n1.z = fmaf(cc, l1c.z - oc * h1c.z, h1c.z);
    n1.w = fmaf(cc, l1c.w - oc * h1c.w, h1c.w);
    __builtin_nontemporal_store(n0, (v4f*)(hebb_new + hc + k0));
    __builtin_nontemporal_store(n1, (v4f*)(hebb_new + hc + k1));

    n0.x = fmaf(cd, l0d.x - od * h0d.x, h0d.x);
    n0.y = fmaf(cd, l0d.y - od * h0d.y, h0d.y);
    n0.z = fmaf(cd, l0d.z - od * h0d.z, h0d.z);
    n0.w = fmaf(cd, l0d.w - od * h0d.w, h0d.w);
    n1.x = fmaf(cd, l1d.x - od * h1d.x, h1d.x);
    n1.y = fmaf(cd, l1d.y - od * h1d.y, h1d.y);
    n1.z = fmaf(cd, l1d.z - od * h1d.z, h1d.z);
    n1.w = fmaf(cd, l1d.w - od * h1d.w, h1d.w);
    __builtin_nontemporal_store(n0, (v4f*)(hebb_new + hd + k0));
    __builtin_nontemporal_store(n1, (v4f*)(hebb_new + hd + k1));
}

extern "C" void kernel_launch(void* const* d_in, const int* in_sizes, int n_in,
                              void* d_out, int out_size, void* d_ws, size_t ws_size,
                              hipStream_t stream) {
    const float* input    = (const float*)d_in[0];
    const float* last_out = (const float*)d_in[1];
    const float* hebb     = (const float*)d_in[2];
    const float* weight   = (const float*)d_in[3];
    const float* ps       = (const float*)d_in[4];
    const float* lr       = (const float*)d_in[5];

    float* out      = (float*)d_out;            // first B*F floats
    float* hebb_new = out + BB * FF;            // then B*F*F floats

    const int blocks = 16384 / 4;               // 4096 blocks, 4 waves, 4 rows/wave

    PlasticLinearRec_kernel<<<blocks, 256, 0, stream>>>(
        input, last_out, hebb, weight, ps, lr, out, hebb_new);
}

// Round 8
// 232.557 us; speedup vs baseline: 1.0233x; 1.0233x over previous
//
#include <hip/hip_runtime.h>

#define BB 128
#define FF 512

typedef float v4f __attribute__((ext_vector_type(4)));

// FINAL (r6 config, reverted after r7's n=4 null): fused, NT hebb
// load/store, 2 rows per wave. Rows r and r+32768 share j (32768 = 64*512):
// weight/ps loaded once per wave for both rows. All 12 vector loads issue
// before either reduce; two 8-FMA chains and two 6-step butterflies
// interleave (2x ILP); wave holds 4 KB of hebb reads in flight.
// MLP curve mapped: 1 row/wave ~79.6us, 2 rows ~72us (best), 4 rows ~75us
// (VGPR cost cuts occupancy; per-CU in-flight bytes saturate). All other
// levers exhausted: scheduling structure (one-shot/persistent/split all
// equal), caching policy (NT beats cached while moving 30% MORE HBM bytes
// -> not HBM-byte-bound), every PMC pipe idle. ~72us is the kernel floor;
// the other 160.5us of dur_us is the harness's two poison fills at 84% of
// HBM write peak.
__global__ __launch_bounds__(256) void PlasticLinearRec_kernel(
    const float* __restrict__ input,
    const float* __restrict__ last_out,
    const float* __restrict__ hebb,
    const float* __restrict__ weight,
    const float* __restrict__ ps,
    const float* __restrict__ lr_p,
    float* __restrict__ out,       // B*F
    float* __restrict__ hebb_new)  // B*F*F
{
    const int wave = threadIdx.x >> 6;
    const int lane = threadIdx.x & 63;
    const int wid  = blockIdx.x * 4 + wave;     // 0 .. 32767
    const int j    = wid & (FF - 1);
    const int ba   = wid >> 9;                  // 0..63
    const int bb   = ba + 64;                   // 64..127

    const int k0 = lane * 4;
    const int k1 = 256 + lane * 4;

    const size_t ha = (size_t)wid * FF;             // hebb row (ba, j)
    const size_t hb = ha + (size_t)32768 * FF;      // hebb row (bb, j)
    const int    wb = j * FF;
    const int    la = ba * FF;
    const int    lb = bb * FF;

    // ---- issue ALL loads up front (12 vector + 2 scalar) ----
    const v4f h0a = __builtin_nontemporal_load((const v4f*)(hebb + ha + k0));
    const v4f h1a = __builtin_nontemporal_load((const v4f*)(hebb + ha + k1));
    const v4f h0b = __builtin_nontemporal_load((const v4f*)(hebb + hb + k0));
    const v4f h1b = __builtin_nontemporal_load((const v4f*)(hebb + hb + k1));
    const v4f w0  = *(const v4f*)(weight   + wb + k0);
    const v4f w1  = *(const v4f*)(weight   + wb + k1);
    const v4f p0  = *(const v4f*)(ps       + wb + k0);
    const v4f p1  = *(const v4f*)(ps       + wb + k1);
    const v4f l0a = *(const v4f*)(last_out + la + k0);
    const v4f l1a = *(const v4f*)(last_out + la + k1);
    const v4f l0b = *(const v4f*)(last_out + lb + k0);
    const v4f l1b = *(const v4f*)(last_out + lb + k1);
    const float ia = input[la + j];
    const float ib = input[lb + j];
    const float lr = lr_p[0];

    // ---- two independent FMA chains (interleaved by the scheduler) ----
    float aa, ab;
    aa = l0a.x * fmaf(p0.x, h0a.x, w0.x);
    ab = l0b.x * fmaf(p0.x, h0b.x, w0.x);
    aa = fmaf(l0a.y, fmaf(p0.y, h0a.y, w0.y), aa);
    ab = fmaf(l0b.y, fmaf(p0.y, h0b.y, w0.y), ab);
    aa = fmaf(l0a.z, fmaf(p0.z, h0a.z, w0.z), aa);
    ab = fmaf(l0b.z, fmaf(p0.z, h0b.z, w0.z), ab);
    aa = fmaf(l0a.w, fmaf(p0.w, h0a.w, w0.w), aa);
    ab = fmaf(l0b.w, fmaf(p0.w, h0b.w, w0.w), ab);
    aa = fmaf(l1a.x, fmaf(p1.x, h1a.x, w1.x), aa);
    ab = fmaf(l1b.x, fmaf(p1.x, h1b.x, w1.x), ab);
    aa = fmaf(l1a.y, fmaf(p1.y, h1a.y, w1.y), aa);
    ab = fmaf(l1b.y, fmaf(p1.y, h1b.y, w1.y), ab);
    aa = fmaf(l1a.z, fmaf(p1.z, h1a.z, w1.z), aa);
    ab = fmaf(l1b.z, fmaf(p1.z, h1b.z, w1.z), ab);
    aa = fmaf(l1a.w, fmaf(p1.w, h1a.w, w1.w), aa);
    ab = fmaf(l1b.w, fmaf(p1.w, h1b.w, w1.w), ab);

    // ---- two interleaved 64-lane butterflies ----
    #pragma unroll
    for (int off = 32; off > 0; off >>= 1) {
        aa += __shfl_xor(aa, off, 64);
        ab += __shfl_xor(ab, off, 64);
    }

    const float oa = tanhf(aa + ia);
    const float ob = tanhf(ab + ib);
    const float ca = lr * oa;
    const float cb = lr * ob;

    if (lane == 0) {
        out[la + j] = oa;
        out[lb + j] = ob;
    }

    v4f n0, n1;
    n0.x = fmaf(ca, l0a.x - oa * h0a.x, h0a.x);
    n0.y = fmaf(ca, l0a.y - oa * h0a.y, h0a.y);
    n0.z = fmaf(ca, l0a.z - oa * h0a.z, h0a.z);
    n0.w = fmaf(ca, l0a.w - oa * h0a.w, h0a.w);
    n1.x = fmaf(ca, l1a.x - oa * h1a.x, h1a.x);
    n1.y = fmaf(ca, l1a.y - oa * h1a.y, h1a.y);
    n1.z = fmaf(ca, l1a.z - oa * h1a.z, h1a.z);
    n1.w = fmaf(ca, l1a.w - oa * h1a.w, h1a.w);
    __builtin_nontemporal_store(n0, (v4f*)(hebb_new + ha + k0));
    __builtin_nontemporal_store(n1, (v4f*)(hebb_new + ha + k1));

    n0.x = fmaf(cb, l0b.x - ob * h0b.x, h0b.x);
    n0.y = fmaf(cb, l0b.y - ob * h0b.y, h0b.y);
    n0.z = fmaf(cb, l0b.z - ob * h0b.z, h0b.z);
    n0.w = fmaf(cb, l0b.w - ob * h0b.w, h0b.w);
    n1.x = fmaf(cb, l1b.x - ob * h1b.x, h1b.x);
    n1.y = fmaf(cb, l1b.y - ob * h1b.y, h1b.y);
    n1.z = fmaf(cb, l1b.z - ob * h1b.z, h1b.z);
    n1.w = fmaf(cb, l1b.w - ob * h1b.w, h1b.w);
    __builtin_nontemporal_store(n0, (v4f*)(hebb_new + hb + k0));
    __builtin_nontemporal_store(n1, (v4f*)(hebb_new + hb + k1));
}

extern "C" void kernel_launch(void* const* d_in, const int* in_sizes, int n_in,
                              void* d_out, int out_size, void* d_ws, size_t ws_size,
                              hipStream_t stream) {
    const float* input    = (const float*)d_in[0];
    const float* last_out = (const float*)d_in[1];
    const float* hebb     = (const float*)d_in[2];
    const float* weight   = (const float*)d_in[3];
    const float* ps       = (const float*)d_in[4];
    const float* lr       = (const float*)d_in[5];

    float* out      = (float*)d_out;            // first B*F floats
    float* hebb_new = out + BB * FF;            // then B*F*F floats

    const int blocks = 32768 / 4;               // 8192 blocks, 4 waves, 2 rows/wave

    PlasticLinearRec_kernel<<<blocks, 256, 0, stream>>>(
        input, last_out, hebb, weight, ps, lr, out, hebb_new);
}